// Round 4
// baseline (159.171 us; speedup 1.0000x reference)
//
#include <hip/hip_runtime.h>

#define LSZ 1024
#define EPS 1e-8f

struct c32 { float re, im; };

__device__ __forceinline__ c32 cmul(c32 a, c32 b) {
    return { a.re * b.re - a.im * b.im, a.re * b.im + a.im * b.re };
}
// a * conj(b)
__device__ __forceinline__ c32 cmulc(c32 a, c32 b) {
    return { a.re * b.re + a.im * b.im, a.im * b.re - a.re * b.im };
}
__device__ __forceinline__ c32 cadd(c32 a, c32 b) {
    return { a.re + b.re, a.im + b.im };
}

__device__ __forceinline__ float3 ld_theta(const float* __restrict__ theta,
                                           int sx, int sy) {
    const float* t = theta + 3 * (sx * LSZ + sy);
    return make_float3(t[0], t[1], t[2]);
}

// g = cos(n) I + i sinc(n) (theta . sigma), from a preloaded theta triple.
// Native sin/cos + v_rcp: theta-norms are <= ~7, trivially in fast range.
__device__ __forceinline__ void make_g(float3 t, c32 g[2][2]) {
    float n2 = t.x * t.x + t.y * t.y + t.z * t.z;
    float n  = __builtin_amdgcn_sqrtf(n2);
    float c  = __cosf(n);
    float sn = __sinf(n);
    float s  = (n > EPS) ? (sn * __builtin_amdgcn_rcpf(n)) : 1.0f;
    float a1 = s * t.x, a2 = s * t.y, a3 = s * t.z;
    g[0][0] = {  c,  a3 };
    g[0][1] = {  a2, a1 };
    g[1][0] = { -a2, a1 };
    g[1][1] = {  c, -a3 };
}

// Ut = g @ M @ gn^dagger ; return sum |P - Ut|^2 over the 4 entries
__device__ __forceinline__ float site_mu_loss(const c32 g[2][2], const c32 gn[2][2],
                                              float4 m0, float4 m1,
                                              float4 p0, float4 p1) {
    c32 M[2][2] = { { { m0.x, m0.y }, { m0.z, m0.w } },
                    { { m1.x, m1.y }, { m1.z, m1.w } } };
    c32 P[2][2] = { { { p0.x, p0.y }, { p0.z, p0.w } },
                    { { p1.x, p1.y }, { p1.z, p1.w } } };
    c32 T[2][2];
#pragma unroll
    for (int a = 0; a < 2; ++a)
#pragma unroll
        for (int cc = 0; cc < 2; ++cc)
            T[a][cc] = cadd(cmul(g[a][0], M[0][cc]), cmul(g[a][1], M[1][cc]));

    float acc = 0.0f;
#pragma unroll
    for (int a = 0; a < 2; ++a)
#pragma unroll
        for (int d = 0; d < 2; ++d) {
            c32 ut = cadd(cmulc(T[a][0], gn[d][0]), cmulc(T[a][1], gn[d][1]));
            float dr = P[a][d].re - ut.re;
            float di = P[a][d].im - ut.im;
            acc += dr * dr + di * di;
        }
    return acc;
}

__global__ void zero_out_kernel(float* out) {
    if (threadIdx.x == 0) out[0] = 0.0f;
}

// Two sites per thread. sched_barrier(0) after the load block FORCES the
// scheduler to keep all 22 loads issued before any compute (round 2/3 showed
// it otherwise sinks loads to their uses, serializing them through 36 VGPRs).
// All load results live at once -> full per-wave MLP; sin/cos chains execute
// in the U-load shadow via partial vmcnt waits.
__global__ __launch_bounds__(256, 2) void gauge_loss_kernel(
    const float* __restrict__ theta,
    const float* __restrict__ U_pred,
    const float* __restrict__ U_true,
    float* __restrict__ out) {
    const int i0 = blockIdx.x * 512 + threadIdx.x;   // site A
    const int i1 = i0 + 256;                         // site B

    // ---- site coordinates ----
    int xa = i0 >> 10, ya = i0 & (LSZ - 1);
    int xb = i1 >> 10, yb = i1 & (LSZ - 1);
    int xap = (xa + 1) & (LSZ - 1), yap = (ya + 1) & (LSZ - 1);
    int xbp = (xb + 1) & (LSZ - 1), ybp = (yb + 1) & (LSZ - 1);

    // ---- issue ALL loads: 16 x float4 (U) + 6 x float3 (theta) ----
    const float4* Ta = (const float4*)U_true + (size_t)i0 * 4;
    const float4* Pa = (const float4*)U_pred + (size_t)i0 * 4;
    const float4* Tb = (const float4*)U_true + (size_t)i1 * 4;
    const float4* Pb = (const float4*)U_pred + (size_t)i1 * 4;
    float4 ta0 = Ta[0], ta1 = Ta[1], ta2 = Ta[2], ta3 = Ta[3];
    float4 pa0 = Pa[0], pa1 = Pa[1], pa2 = Pa[2], pa3 = Pa[3];
    float4 tb0 = Tb[0], tb1 = Tb[1], tb2 = Tb[2], tb3 = Tb[3];
    float4 pb0 = Pb[0], pb1 = Pb[1], pb2 = Pb[2], pb3 = Pb[3];

    float3 th_a  = ld_theta(theta, xa,  ya);
    float3 th_ax = ld_theta(theta, xap, ya);
    float3 th_ay = ld_theta(theta, xa,  yap);
    float3 th_b  = ld_theta(theta, xb,  yb);
    float3 th_bx = ld_theta(theta, xbp, yb);
    float3 th_by = ld_theta(theta, xb,  ybp);

    // Nothing may cross: loads stay above, compute stays below.
    __builtin_amdgcn_sched_barrier(0);

    // ---- compute g matrices (depend only on theta loads; overlap U latency) ----
    c32 ga[2][2], gax[2][2], gay[2][2], gb[2][2], gbx[2][2], gby[2][2];
    make_g(th_a,  ga);
    make_g(th_ax, gax);
    make_g(th_ay, gay);
    make_g(th_b,  gb);
    make_g(th_bx, gbx);
    make_g(th_by, gby);

    float acc = site_mu_loss(ga, gax, ta0, ta1, pa0, pa1)   // site A, mu=0
              + site_mu_loss(ga, gay, ta2, ta3, pa2, pa3)   // site A, mu=1
              + site_mu_loss(gb, gbx, tb0, tb1, pb0, pb1)   // site B, mu=0
              + site_mu_loss(gb, gby, tb2, tb3, pb2, pb3);  // site B, mu=1

    // fold: mean over 4 entries (1/4) and final /(L*L*2)
    acc *= (1.0f / (8.0f * (float)LSZ * (float)LSZ));

    // wave (64-lane) shuffle reduction
#pragma unroll
    for (int off = 32; off > 0; off >>= 1)
        acc += __shfl_down(acc, off, 64);

    __shared__ float wave_sums[4];
    int lane = threadIdx.x & 63;
    int wave = threadIdx.x >> 6;
    if (lane == 0) wave_sums[wave] = acc;
    __syncthreads();
    if (threadIdx.x == 0) {
        float s = wave_sums[0] + wave_sums[1] + wave_sums[2] + wave_sums[3];
        atomicAdd(out, s);
    }
}

extern "C" void kernel_launch(void* const* d_in, const int* in_sizes, int n_in,
                              void* d_out, int out_size, void* d_ws, size_t ws_size,
                              hipStream_t stream) {
    const float* theta  = (const float*)d_in[0];
    const float* U_pred = (const float*)d_in[1];
    const float* U_true = (const float*)d_in[2];
    float* out = (float*)d_out;

    zero_out_kernel<<<1, 64, 0, stream>>>(out);

    const int n_sites = LSZ * LSZ;
    gauge_loss_kernel<<<n_sites / 512, 256, 0, stream>>>(theta, U_pred, U_true, out);
}

// Round 5
// 156.745 us; speedup vs baseline: 1.0155x; 1.0155x over previous
//
#include <hip/hip_runtime.h>

#define LSZ 1024
#define EPS 1e-8f
#define NBLK 4096

struct c32 { float re, im; };

__device__ __forceinline__ c32 cmul(c32 a, c32 b) {
    return { a.re * b.re - a.im * b.im, a.re * b.im + a.im * b.re };
}
// a * conj(b)
__device__ __forceinline__ c32 cmulc(c32 a, c32 b) {
    return { a.re * b.re + a.im * b.im, a.im * b.re - a.re * b.im };
}
__device__ __forceinline__ c32 cadd(c32 a, c32 b) {
    return { a.re + b.re, a.im + b.im };
}

// g = cos(n) I + i sinc(n) (theta . sigma). Native sin/cos/rcp: theta norms
// are <= ~7 (3 gaussians), safely in fast range; error ~1e-6 << 8e-2 thresh.
__device__ __forceinline__ void make_g(const float* __restrict__ theta,
                                       int sx, int sy, c32 g[2][2]) {
    const float* t = theta + 3 * (sx * LSZ + sy);
    float t1 = t[0], t2 = t[1], t3 = t[2];
    float n2 = t1 * t1 + t2 * t2 + t3 * t3;
    float n  = __builtin_amdgcn_sqrtf(n2);
    float c  = __cosf(n);
    float sn = __sinf(n);
    float s  = (n > EPS) ? (sn * __builtin_amdgcn_rcpf(n)) : 1.0f;
    float a1 = s * t1, a2 = s * t2, a3 = s * t3;
    g[0][0] = {  c,  a3 };
    g[0][1] = {  a2, a1 };
    g[1][0] = { -a2, a1 };
    g[1][1] = {  c, -a3 };
}

// Ut = g @ M @ gn^dagger ; return sum |P - Ut|^2 over the 4 entries
__device__ __forceinline__ float site_mu_loss(const c32 g[2][2], const c32 gn[2][2],
                                              float4 m0, float4 m1,
                                              float4 p0, float4 p1) {
    c32 M[2][2] = { { { m0.x, m0.y }, { m0.z, m0.w } },
                    { { m1.x, m1.y }, { m1.z, m1.w } } };
    c32 P[2][2] = { { { p0.x, p0.y }, { p0.z, p0.w } },
                    { { p1.x, p1.y }, { p1.z, p1.w } } };
    c32 T[2][2];
#pragma unroll
    for (int a = 0; a < 2; ++a)
#pragma unroll
        for (int cc = 0; cc < 2; ++cc)
            T[a][cc] = cadd(cmul(g[a][0], M[0][cc]), cmul(g[a][1], M[1][cc]));

    float acc = 0.0f;
#pragma unroll
    for (int a = 0; a < 2; ++a)
#pragma unroll
        for (int d = 0; d < 2; ++d) {
            c32 ut = cadd(cmulc(T[a][0], gn[d][0]), cmulc(T[a][1], gn[d][1]));
            float dr = P[a][d].re - ut.re;
            float di = P[a][d].im - ut.im;
            acc += dr * dr + di * di;
        }
    return acc;
}

// One site per thread, 4096 blocks (16/CU -> multiple resident generations so
// stall phases of different blocks interleave). NO atomics: per-block partial
// sums go to d_ws; a second 1-block kernel reduces them and overwrites out[0]
// (removes both the 2048-way same-address atomic tail and the zero_out
// dispatch that rounds 1-4 carried).
__global__ __launch_bounds__(256) void gauge_loss_kernel(
    const float* __restrict__ theta,
    const float* __restrict__ U_pred,
    const float* __restrict__ U_true,
    float* __restrict__ partial) {
    const int idx = blockIdx.x * 256 + threadIdx.x;  // site index
    int x = idx >> 10;
    int y = idx & (LSZ - 1);
    int xp = (x + 1) & (LSZ - 1);
    int yp = (y + 1) & (LSZ - 1);

    // U payload: 16 contiguous floats per site = 4 x float4
    const float4* Ut4 = (const float4*)U_true + (size_t)idx * 4;
    const float4* Up4 = (const float4*)U_pred + (size_t)idx * 4;
    float4 t0 = Ut4[0], t1 = Ut4[1], t2 = Ut4[2], t3 = Ut4[3];
    float4 p0 = Up4[0], p1 = Up4[1], p2 = Up4[2], p3 = Up4[3];

    c32 g[2][2], gx[2][2], gy[2][2];
    make_g(theta, x,  y,  g);
    make_g(theta, xp, y,  gx);
    make_g(theta, x,  yp, gy);

    float acc = site_mu_loss(g, gx, t0, t1, p0, p1)    // mu = 0
              + site_mu_loss(g, gy, t2, t3, p2, p3);   // mu = 1

    // fold: mean over 4 entries (1/4) and final /(L*L*2)
    acc *= (1.0f / (8.0f * (float)LSZ * (float)LSZ));

    // wave (64-lane) shuffle reduction
#pragma unroll
    for (int off = 32; off > 0; off >>= 1)
        acc += __shfl_down(acc, off, 64);

    __shared__ float wave_sums[4];
    int lane = threadIdx.x & 63;
    int wave = threadIdx.x >> 6;
    if (lane == 0) wave_sums[wave] = acc;
    __syncthreads();
    if (threadIdx.x == 0)
        partial[blockIdx.x] = wave_sums[0] + wave_sums[1] + wave_sums[2] + wave_sums[3];
}

__global__ __launch_bounds__(256) void reduce_kernel(const float* __restrict__ partial,
                                                     float* __restrict__ out) {
    float s = 0.0f;
#pragma unroll
    for (int i = 0; i < NBLK / 256; ++i)
        s += partial[i * 256 + threadIdx.x];

#pragma unroll
    for (int off = 32; off > 0; off >>= 1)
        s += __shfl_down(s, off, 64);

    __shared__ float wave_sums[4];
    int lane = threadIdx.x & 63;
    int wave = threadIdx.x >> 6;
    if (lane == 0) wave_sums[wave] = s;
    __syncthreads();
    if (threadIdx.x == 0)
        out[0] = wave_sums[0] + wave_sums[1] + wave_sums[2] + wave_sums[3];
}

extern "C" void kernel_launch(void* const* d_in, const int* in_sizes, int n_in,
                              void* d_out, int out_size, void* d_ws, size_t ws_size,
                              hipStream_t stream) {
    const float* theta  = (const float*)d_in[0];
    const float* U_pred = (const float*)d_in[1];
    const float* U_true = (const float*)d_in[2];
    float* out = (float*)d_out;
    float* partial = (float*)d_ws;  // NBLK floats

    gauge_loss_kernel<<<NBLK, 256, 0, stream>>>(theta, U_pred, U_true, partial);
    reduce_kernel<<<1, 256, 0, stream>>>(partial, out);
}

// Round 7
// 156.661 us; speedup vs baseline: 1.0160x; 1.0005x over previous
//
#include <hip/hip_runtime.h>

#define LSZ 1024
#define EPS 1e-8f
#define NBLK 4096

struct c32 { float re, im; };

__device__ __forceinline__ c32 cmul(c32 a, c32 b) {
    return { a.re * b.re - a.im * b.im, a.re * b.im + a.im * b.re };
}
// a * conj(b)
__device__ __forceinline__ c32 cmulc(c32 a, c32 b) {
    return { a.re * b.re + a.im * b.im, a.im * b.re - a.re * b.im };
}
__device__ __forceinline__ c32 cadd(c32 a, c32 b) {
    return { a.re + b.re, a.im + b.im };
}

// ---- forced-MLP loads: inline asm so the pre-RA scheduler CANNOT sink ----
// ---- them to their uses (R2-R5: every C-level variant got re-serialized ----
// ---- through ~28 VGPRs => ~1.6 TB/s request-rate wall). ----
__device__ __forceinline__ void ld_u4(unsigned long long addr,
                                      float4& r0, float4& r1, float4& r2, float4& r3) {
    asm volatile("global_load_dwordx4 %0, %4, off\n\t"
                 "global_load_dwordx4 %1, %4, off offset:16\n\t"
                 "global_load_dwordx4 %2, %4, off offset:32\n\t"
                 "global_load_dwordx4 %3, %4, off offset:48"
                 : "=v"(r0), "=v"(r1), "=v"(r2), "=v"(r3)
                 : "v"(addr));
}
__device__ __forceinline__ void ld_th(unsigned long long addr,
                                      float& a, float& b, float& c) {
    asm volatile("global_load_dword %0, %3, off\n\t"
                 "global_load_dword %1, %3, off offset:4\n\t"
                 "global_load_dword %2, %3, off offset:8"
                 : "=v"(a), "=v"(b), "=v"(c)
                 : "v"(addr));
}

// g = cos(n) I + i sinc(n) (theta . sigma). Native sin/cos/rcp: theta norms
// are <= ~7 (3 gaussians), safely in fast range; error ~1e-6 << 8e-2 thresh.
__device__ __forceinline__ void make_g(float t1, float t2, float t3, c32 g[2][2]) {
    float n2 = t1 * t1 + t2 * t2 + t3 * t3;
    float n  = __builtin_amdgcn_sqrtf(n2);
    float c  = __cosf(n);
    float sn = __sinf(n);
    float s  = (n > EPS) ? (sn * __builtin_amdgcn_rcpf(n)) : 1.0f;
    float a1 = s * t1, a2 = s * t2, a3 = s * t3;
    g[0][0] = {  c,  a3 };
    g[0][1] = {  a2, a1 };
    g[1][0] = { -a2, a1 };
    g[1][1] = {  c, -a3 };
}

// Ut = g @ M @ gn^dagger ; return sum |P - Ut|^2 over the 4 entries
__device__ __forceinline__ float site_mu_loss(const c32 g[2][2], const c32 gn[2][2],
                                              float4 m0, float4 m1,
                                              float4 p0, float4 p1) {
    c32 M[2][2] = { { { m0.x, m0.y }, { m0.z, m0.w } },
                    { { m1.x, m1.y }, { m1.z, m1.w } } };
    c32 P[2][2] = { { { p0.x, p0.y }, { p0.z, p0.w } },
                    { { p1.x, p1.y }, { p1.z, p1.w } } };
    c32 T[2][2];
#pragma unroll
    for (int a = 0; a < 2; ++a)
#pragma unroll
        for (int cc = 0; cc < 2; ++cc)
            T[a][cc] = cadd(cmul(g[a][0], M[0][cc]), cmul(g[a][1], M[1][cc]));

    float acc = 0.0f;
#pragma unroll
    for (int a = 0; a < 2; ++a)
#pragma unroll
        for (int d = 0; d < 2; ++d) {
            c32 ut = cadd(cmulc(T[a][0], gn[d][0]), cmulc(T[a][1], gn[d][1]));
            float dr = P[a][d].re - ut.re;
            float di = P[a][d].im - ut.im;
            acc += dr * dr + di * di;
        }
    return acc;
}

__global__ __launch_bounds__(256) void gauge_loss_kernel(
    const float* __restrict__ theta,
    const float* __restrict__ U_pred,
    const float* __restrict__ U_true,
    float* __restrict__ partial) {
    const int idx = blockIdx.x * 256 + threadIdx.x;  // site index
    int x = idx >> 10;
    int y = idx & (LSZ - 1);
    int xp = (x + 1) & (LSZ - 1);
    int yp = (y + 1) & (LSZ - 1);

    // ---- issue theta loads FIRST (they feed the longest dependent chain) ----
    unsigned long long th_a  = (unsigned long long)(uintptr_t)(theta + 3 * (x  * LSZ + y));
    unsigned long long th_ax = (unsigned long long)(uintptr_t)(theta + 3 * (xp * LSZ + y));
    unsigned long long th_ay = (unsigned long long)(uintptr_t)(theta + 3 * (x  * LSZ + yp));
    float a1, a2, a3, b1, b2, b3, c1, c2, c3;
    ld_th(th_a,  a1, a2, a3);
    ld_th(th_ax, b1, b2, b3);
    ld_th(th_ay, c1, c2, c3);

    // ---- then 8 dwordx4 U loads (16 floats per site, one base per array) ----
    unsigned long long ut_addr = (unsigned long long)(uintptr_t)(U_true + (size_t)idx * 16);
    unsigned long long up_addr = (unsigned long long)(uintptr_t)(U_pred + (size_t)idx * 16);
    float4 t0, t1, t2, t3, p0, p1, p2, p3;
    ld_u4(ut_addr, t0, t1, t2, t3);
    ld_u4(up_addr, p0, p1, p2, p3);

    // wait for the 9 theta dwords only (8 U loads still in flight).
    // scalar ties only: float4 ("indirect") operands cannot be tied on gfx950.
    asm volatile("s_waitcnt vmcnt(8)"
                 : "+v"(a1), "+v"(a2), "+v"(a3),
                   "+v"(b1), "+v"(b2), "+v"(b3),
                   "+v"(c1), "+v"(c2), "+v"(c3));

    // g matrices overlap the U-load latency
    c32 g[2][2], gx[2][2], gy[2][2];
    make_g(a1, a2, a3, g);
    make_g(b1, b2, b3, gx);
    make_g(c1, c2, c3, gy);

    // drain the U loads; tie U_true scalars to the waitcnt itself...
    asm volatile("s_waitcnt vmcnt(0)"
                 : "+v"(t0.x), "+v"(t0.y), "+v"(t0.z), "+v"(t0.w),
                   "+v"(t1.x), "+v"(t1.y), "+v"(t1.z), "+v"(t1.w),
                   "+v"(t2.x), "+v"(t2.y), "+v"(t2.z), "+v"(t2.w),
                   "+v"(t3.x), "+v"(t3.y), "+v"(t3.z), "+v"(t3.w));
    // ...and order the U_pred scalars behind it with an empty volatile asm
    // (no instruction emitted; volatile ordering + outputs force uses after).
    asm volatile(""
                 : "+v"(p0.x), "+v"(p0.y), "+v"(p0.z), "+v"(p0.w),
                   "+v"(p1.x), "+v"(p1.y), "+v"(p1.z), "+v"(p1.w),
                   "+v"(p2.x), "+v"(p2.y), "+v"(p2.z), "+v"(p2.w),
                   "+v"(p3.x), "+v"(p3.y), "+v"(p3.z), "+v"(p3.w));

    float acc = site_mu_loss(g, gx, t0, t1, p0, p1)    // mu = 0
              + site_mu_loss(g, gy, t2, t3, p2, p3);   // mu = 1

    // fold: mean over 4 entries (1/4) and final /(L*L*2)
    acc *= (1.0f / (8.0f * (float)LSZ * (float)LSZ));

    // wave (64-lane) shuffle reduction
#pragma unroll
    for (int off = 32; off > 0; off >>= 1)
        acc += __shfl_down(acc, off, 64);

    __shared__ float wave_sums[4];
    int lane = threadIdx.x & 63;
    int wave = threadIdx.x >> 6;
    if (lane == 0) wave_sums[wave] = acc;
    __syncthreads();
    if (threadIdx.x == 0)
        partial[blockIdx.x] = wave_sums[0] + wave_sums[1] + wave_sums[2] + wave_sums[3];
}

__global__ __launch_bounds__(256) void reduce_kernel(const float* __restrict__ partial,
                                                     float* __restrict__ out) {
    float s = 0.0f;
#pragma unroll
    for (int i = 0; i < NBLK / 256; ++i)
        s += partial[i * 256 + threadIdx.x];

#pragma unroll
    for (int off = 32; off > 0; off >>= 1)
        s += __shfl_down(s, off, 64);

    __shared__ float wave_sums[4];
    int lane = threadIdx.x & 63;
    int wave = threadIdx.x >> 6;
    if (lane == 0) wave_sums[wave] = s;
    __syncthreads();
    if (threadIdx.x == 0)
        out[0] = wave_sums[0] + wave_sums[1] + wave_sums[2] + wave_sums[3];
}

extern "C" void kernel_launch(void* const* d_in, const int* in_sizes, int n_in,
                              void* d_out, int out_size, void* d_ws, size_t ws_size,
                              hipStream_t stream) {
    const float* theta  = (const float*)d_in[0];
    const float* U_pred = (const float*)d_in[1];
    const float* U_true = (const float*)d_in[2];
    float* out = (float*)d_out;
    float* partial = (float*)d_ws;  // NBLK floats

    gauge_loss_kernel<<<NBLK, 256, 0, stream>>>(theta, U_pred, U_true, partial);
    reduce_kernel<<<1, 256, 0, stream>>>(partial, out);
}